// Round 1
// baseline (5174.372 us; speedup 1.0000x reference)
//
#include <hip/hip_runtime.h>
#include <math.h>

// ---------------------------------------------------------------------------
// MPNN (NNConv+GRU x3, Set2Set x3, readout) — fp32 correctness-first version.
// N=20000 nodes, E=60000 edges, DIM=64, B=512 graphs.
// ---------------------------------------------------------------------------

#define TILE_E 64

// graph segment pointers from sorted batch: gptr[b] = first node with batch>=b
__global__ void k_gptr(const int* __restrict__ batch, int* __restrict__ gptr,
                       int N, int B) {
  int n = blockIdx.x * 256 + threadIdx.x;
  if (n >= N) return;
  int b = batch[n];
  int bp = (n == 0) ? -1 : batch[n - 1];
  for (int g = bp + 1; g <= b; ++g) gptr[g] = n;
  if (n == N - 1) {
    for (int g = b + 1; g <= B; ++g) gptr[g] = N;
  }
}

__global__ void k_deg(const int* __restrict__ eidx, float* __restrict__ deg, int E) {
  int e = blockIdx.x * 256 + threadIdx.x;
  if (e < E) atomicAdd(&deg[eidx[E + e]], 1.0f);
}

// out = relu(x @ lin0_w^T + lin0_b) : thread per (n,d)
__global__ void k_lin0(const float* __restrict__ x, const float* __restrict__ w,
                       const float* __restrict__ b, float* __restrict__ outn, int N) {
  int gid = blockIdx.x * 256 + threadIdx.x;
  int n = gid >> 6, d = gid & 63;
  if (n >= N) return;
  const float* xr = x + (size_t)n * 11;
  const float* wr = w + d * 11;
  float acc = b[d];
#pragma unroll
  for (int f = 0; f < 11; ++f) acc += xr[f] * wr[f];
  outn[(size_t)n * 64 + d] = fmaxf(acc, 0.f);
}

// NNConv message: per 64-edge tile, recompute h1 = relu(ea@nn1^T+b1) into LDS,
// loop i over 64: stage W2 slab [k][o] (XOR-swizzled) in LDS, accumulate
// msg[e,o] += s[e,i]*(sum_k W2[i*64+o,k]*h1[e,k] + b2[i*64+o]); scatter to agg.
__global__ __launch_bounds__(256) void k_msg(
    const float* __restrict__ eattr, const int* __restrict__ eidx,
    const float* __restrict__ nn1_w, const float* __restrict__ nn1_b,
    const float* __restrict__ nn2_w, const float* __restrict__ nn2_b,
    const float* __restrict__ outn, float* __restrict__ agg, int E) {
  __shared__ __align__(16) float wlds[128 * 64];   // [k][o] group-XOR swizzled
  __shared__ __align__(16) float h1lds[64 * 128];  // [e][k] kg-XOR swizzled by e

  const int t = threadIdx.x;
  const int e0 = blockIdx.x * TILE_E;
  const int oi = t & 15;   // o-group: outputs 4*oi .. 4*oi+3
  const int o0 = oi << 2;
  const int eg = t >> 4;   // edge group: edges eg*4 .. eg*4+3

  // ---- stage h1 tile (recomputed from edge_attr) ----
  for (int idx = t; idx < TILE_E * 128; idx += 256) {
    int e = idx >> 7, j = idx & 127;
    int ge = e0 + e;
    float v = 0.f;
    if (ge < E) {
      const float* a = eattr + (size_t)ge * 5;
      const float* wr = nn1_w + j * 5;
      v = nn1_b[j] + a[0] * wr[0] + a[1] * wr[1] + a[2] * wr[2] + a[3] * wr[3] +
          a[4] * wr[4];
      v = fmaxf(v, 0.f);
    }
    h1lds[e * 128 + (((j >> 2) ^ (e & 7)) << 2) + (j & 3)] = v;
  }

  // src/dst for my 4 edges
  int srcs[4], dsts[4];
#pragma unroll
  for (int e4 = 0; e4 < 4; ++e4) {
    int ge = e0 + eg * 4 + e4;
    srcs[e4] = (ge < E) ? eidx[ge] : -1;
    dsts[e4] = (ge < E) ? eidx[E + ge] : -1;
  }

  float acc[4][4];
#pragma unroll
  for (int e4 = 0; e4 < 4; ++e4)
#pragma unroll
    for (int j = 0; j < 4; ++j) acc[e4][j] = 0.f;

  for (int i = 0; i < 64; ++i) {
    __syncthreads();
    // stage W2 slab for this i: global rows i*64+row, row=0..63, k=0..127
    {
      const float4* w4 = (const float4*)(nn2_w + (size_t)(i << 6) * 128);
      for (int idx4 = t; idx4 < 2048; idx4 += 256) {
        float4 v = w4[idx4];
        int row = idx4 >> 5;
        int k0 = (idx4 & 31) << 2;
        int r3 = row & 3, rg = row >> 2;
        wlds[(k0 + 0) * 64 + (((rg ^ ((k0 + 0) & 15)) & 15) << 2) + r3] = v.x;
        wlds[(k0 + 1) * 64 + (((rg ^ ((k0 + 1) & 15)) & 15) << 2) + r3] = v.y;
        wlds[(k0 + 2) * 64 + (((rg ^ ((k0 + 2) & 15)) & 15) << 2) + r3] = v.z;
        wlds[(k0 + 3) * 64 + (((rg ^ ((k0 + 3) & 15)) & 15) << 2) + r3] = v.w;
      }
    }
    __syncthreads();

    // s values for this i (global, L1/L2-cached; used after k-loop)
    float sv[4];
#pragma unroll
    for (int e4 = 0; e4 < 4; ++e4)
      sv[e4] = (srcs[e4] >= 0) ? outn[(size_t)srcs[e4] * 64 + i] : 0.f;

    float p[4][4];
#pragma unroll
    for (int e4 = 0; e4 < 4; ++e4)
#pragma unroll
      for (int j = 0; j < 4; ++j) p[e4][j] = 0.f;

    for (int k0 = 0; k0 < 128; k0 += 4) {
      float4 wv[4];
#pragma unroll
      for (int j = 0; j < 4; ++j) {
        int k = k0 + j;
        int og = (oi ^ (k & 15)) & 15;
        wv[j] = *(const float4*)&wlds[k * 64 + (og << 2)];
      }
#pragma unroll
      for (int e4 = 0; e4 < 4; ++e4) {
        int e = eg * 4 + e4;
        float4 hv = *(const float4*)&h1lds[e * 128 +
                                           (((k0 >> 2) ^ (e & 7)) << 2)];
        p[e4][0] += hv.x * wv[0].x + hv.y * wv[1].x + hv.z * wv[2].x + hv.w * wv[3].x;
        p[e4][1] += hv.x * wv[0].y + hv.y * wv[1].y + hv.z * wv[2].y + hv.w * wv[3].y;
        p[e4][2] += hv.x * wv[0].z + hv.y * wv[1].z + hv.z * wv[2].z + hv.w * wv[3].z;
        p[e4][3] += hv.x * wv[0].w + hv.y * wv[1].w + hv.z * wv[2].w + hv.w * wv[3].w;
      }
    }
    float4 bv = *(const float4*)&nn2_b[(i << 6) + o0];
#pragma unroll
    for (int e4 = 0; e4 < 4; ++e4) {
      acc[e4][0] += sv[e4] * (p[e4][0] + bv.x);
      acc[e4][1] += sv[e4] * (p[e4][1] + bv.y);
      acc[e4][2] += sv[e4] * (p[e4][2] + bv.z);
      acc[e4][3] += sv[e4] * (p[e4][3] + bv.w);
    }
  }

  // scatter to agg[dst]
#pragma unroll
  for (int e4 = 0; e4 < 4; ++e4) {
    if (dsts[e4] >= 0) {
      float* ap = agg + (size_t)dsts[e4] * 64 + o0;
      atomicAdd(ap + 0, acc[e4][0]);
      atomicAdd(ap + 1, acc[e4][1]);
      atomicAdd(ap + 2, acc[e4][2]);
      atomicAdd(ap + 3, acc[e4][3]);
    }
  }
}

// m = relu(agg/deg + out@root_w^T + conv_b) : wave per node
__global__ __launch_bounds__(256) void k_conv_m(
    const float* __restrict__ agg, const float* __restrict__ deg,
    const float* __restrict__ root_w, const float* __restrict__ conv_b,
    const float* __restrict__ outn, float* __restrict__ m_out, int N) {
  __shared__ float rootT[64 * 65];  // [k][d], pad 65
  const int t = threadIdx.x;
  for (int idx = t; idx < 4096; idx += 256) {
    int dd = idx >> 6, k = idx & 63;
    rootT[k * 65 + dd] = root_w[idx];
  }
  __syncthreads();
  const int wv = t >> 6, d = t & 63;
  const int n = blockIdx.x * 4 + wv;
  if (n >= N) return;
  float h_d = outn[(size_t)n * 64 + d];
  float acc = agg[(size_t)n * 64 + d] / fmaxf(deg[n], 1.f) + conv_b[d];
#pragma unroll
  for (int k = 0; k < 64; ++k) acc += rootT[k * 65 + d] * __shfl(h_d, k);
  m_out[(size_t)n * 64 + d] = fmaxf(acc, 0.f);
}

// GRU step: out <- GRU(m, h=out). Wave per node; weights staged in LDS in
// k-halves ([kl][g], pad 385 -> conflict-free loads+stores).
__global__ __launch_bounds__(256) void k_gru(
    const float* __restrict__ m_in, const float* __restrict__ gw_ih,
    const float* __restrict__ gw_hh, const float* __restrict__ gb_ih,
    const float* __restrict__ gb_hh, float* __restrict__ outn, int N) {
  __shared__ float wT[32 * 385];  // [kl][0..191]=ih rows, [192..383]=hh rows
  const int t = threadIdx.x;
  const int wv = t >> 6, d = t & 63;
  const int n = blockIdx.x * 4 + wv;
  const bool act = (n < N);
  float m_d = act ? m_in[(size_t)n * 64 + d] : 0.f;
  float h_d = act ? outn[(size_t)n * 64 + d] : 0.f;
  float ir = 0, iz = 0, in_ = 0, hr = 0, hz = 0, hn = 0;
  for (int half = 0; half < 2; ++half) {
    __syncthreads();
    for (int idx = t; idx < 192 * 32; idx += 256) {
      int g = idx >> 5, kl = idx & 31;
      wT[kl * 385 + g] = gw_ih[g * 64 + half * 32 + kl];
      wT[kl * 385 + 192 + g] = gw_hh[g * 64 + half * 32 + kl];
    }
    __syncthreads();
#pragma unroll
    for (int kl = 0; kl < 32; ++kl) {
      int k = half * 32 + kl;
      float mk = __shfl(m_d, k);
      float hk = __shfl(h_d, k);
      const float* row = &wT[kl * 385];
      ir += row[d] * mk;
      iz += row[64 + d] * mk;
      in_ += row[128 + d] * mk;
      hr += row[192 + d] * hk;
      hz += row[256 + d] * hk;
      hn += row[320 + d] * hk;
    }
  }
  if (act) {
    float r = 1.f / (1.f + expf(-(ir + gb_ih[d] + hr + gb_hh[d])));
    float z = 1.f / (1.f + expf(-(iz + gb_ih[64 + d] + hz + gb_hh[64 + d])));
    float nn = tanhf(in_ + gb_ih[128 + d] + r * (hn + gb_hh[128 + d]));
    outn[(size_t)n * 64 + d] = (1.f - z) * nn + z * h_d;
  }
}

// Set2Set LSTM step: block per graph (256 threads = 256 gate units)
__global__ __launch_bounds__(256) void k_lstm(
    const float* __restrict__ w_ih, const float* __restrict__ w_hh,
    const float* __restrict__ b_ih, const float* __restrict__ b_hh,
    const float* __restrict__ qstar, float* __restrict__ hs,
    float* __restrict__ cs) {
  __shared__ float gate[256];
  __shared__ float q[128];
  __shared__ float h[64];
  const int b = blockIdx.x, t = threadIdx.x;
  if (t < 128) q[t] = qstar[b * 128 + t];
  if (t < 64) h[t] = hs[b * 64 + t];
  __syncthreads();
  float acc = b_ih[t] + b_hh[t];
  const float* wi = w_ih + t * 128;
  const float* wh = w_hh + t * 64;
#pragma unroll 4
  for (int k = 0; k < 128; ++k) acc += wi[k] * q[k];
#pragma unroll 4
  for (int k = 0; k < 64; ++k) acc += wh[k] * h[k];
  gate[t] = acc;
  __syncthreads();
  if (t < 64) {
    float ig = gate[t], fg = gate[64 + t], gg = gate[128 + t], og = gate[192 + t];
    float c = cs[b * 64 + t];
    float si = 1.f / (1.f + expf(-ig));
    float sf = 1.f / (1.f + expf(-fg));
    float so = 1.f / (1.f + expf(-og));
    float cn = sf * c + si * tanhf(gg);
    cs[b * 64 + t] = cn;
    hs[b * 64 + t] = so * tanhf(cn);
  }
}

// Set2Set attention: one wave per graph. q = hs; scatter-softmax over segment;
// writes q_star[b] = [q, r].
__global__ __launch_bounds__(64) void k_attn(const float* __restrict__ outn,
                                             const int* __restrict__ gptr,
                                             const float* __restrict__ hs,
                                             float* __restrict__ qstar) {
  const int b = blockIdx.x, d = threadIdx.x;
  const int n0 = gptr[b], n1 = gptr[b + 1];
  float qd = hs[b * 64 + d];
  float mx = -3.4e38f;
  for (int n = n0; n < n1; ++n) {
    float v = outn[(size_t)n * 64 + d] * qd;
    for (int s = 32; s > 0; s >>= 1) v += __shfl_xor(v, s);
    mx = fmaxf(mx, v);
  }
  float denom = 0.f, racc = 0.f;
  for (int n = n0; n < n1; ++n) {
    float od = outn[(size_t)n * 64 + d];
    float v = od * qd;
    for (int s = 32; s > 0; s >>= 1) v += __shfl_xor(v, s);
    float a = expf(v - mx);
    denom += a;
    racc += a * od;
  }
  float r = (denom > 0.f) ? racc / denom : 0.f;
  qstar[b * 128 + d] = qd;
  qstar[b * 128 + 64 + d] = r;
}

// readout: y[b] = relu(q_star@lin1^T+b1)@lin2^T+b2 ; one wave per graph
__global__ __launch_bounds__(64) void k_read(const float* __restrict__ qstar,
                                             const float* __restrict__ w1,
                                             const float* __restrict__ b1,
                                             const float* __restrict__ w2,
                                             const float* __restrict__ b2,
                                             float* __restrict__ y) {
  const int b = blockIdx.x, d = threadIdx.x;
  const float* q = qstar + b * 128;
  const float* wr = w1 + d * 128;
  float acc = b1[d];
#pragma unroll 4
  for (int k = 0; k < 128; ++k) acc += wr[k] * q[k];
  acc = fmaxf(acc, 0.f) * w2[d];
  for (int s = 32; s > 0; s >>= 1) acc += __shfl_xor(acc, s);
  if (d == 0) y[b] = acc + b2[0];
}

extern "C" void kernel_launch(void* const* d_in, const int* in_sizes, int n_in,
                              void* d_out, int out_size, void* d_ws,
                              size_t ws_size, hipStream_t stream) {
  (void)n_in; (void)out_size; (void)ws_size;
  const float* x      = (const float*)d_in[0];
  const int*   eidx   = (const int*)d_in[1];
  const float* eattr  = (const float*)d_in[2];
  const int*   batch  = (const int*)d_in[3];
  const float* lin0_w = (const float*)d_in[4];
  const float* lin0_b = (const float*)d_in[5];
  const float* nn1_w  = (const float*)d_in[6];
  const float* nn1_b  = (const float*)d_in[7];
  const float* nn2_w  = (const float*)d_in[8];
  const float* nn2_b  = (const float*)d_in[9];
  const float* root_w = (const float*)d_in[10];
  const float* conv_b = (const float*)d_in[11];
  const float* gw_ih  = (const float*)d_in[12];
  const float* gw_hh  = (const float*)d_in[13];
  const float* gb_ih  = (const float*)d_in[14];
  const float* gb_hh  = (const float*)d_in[15];
  const float* lw_ih  = (const float*)d_in[16];
  const float* lw_hh  = (const float*)d_in[17];
  const float* lb_ih  = (const float*)d_in[18];
  const float* lb_hh  = (const float*)d_in[19];
  const float* lin1_w = (const float*)d_in[20];
  const float* lin1_b = (const float*)d_in[21];
  const float* lin2_w = (const float*)d_in[22];
  const float* lin2_b = (const float*)d_in[23];

  const int N = in_sizes[0] / 11;
  const int E = in_sizes[1] / 2;
  const int B = 512;

  size_t off = 0;
  auto bump = [&](size_t bytes) {
    size_t o = off;
    off += (bytes + 255) & ~(size_t)255;
    return o;
  };
  char* base = (char*)d_ws;
  float* outn  = (float*)(base + bump((size_t)N * 64 * 4));
  float* agg   = (float*)(base + bump((size_t)N * 64 * 4));
  float* m_buf = (float*)(base + bump((size_t)N * 64 * 4));
  float* deg   = (float*)(base + bump((size_t)N * 4));
  float* qstar = (float*)(base + bump((size_t)B * 128 * 4));
  float* hs    = (float*)(base + bump((size_t)B * 64 * 4));
  float* cs    = (float*)(base + bump((size_t)B * 64 * 4));
  int*   gptr  = (int*)(base + bump((size_t)(B + 1) * 4));

  hipMemsetAsync(deg, 0, (size_t)N * 4, stream);
  hipMemsetAsync(qstar, 0, (size_t)B * 128 * 4, stream);
  hipMemsetAsync(hs, 0, (size_t)B * 64 * 4, stream);
  hipMemsetAsync(cs, 0, (size_t)B * 64 * 4, stream);

  k_gptr<<<(N + 255) / 256, 256, 0, stream>>>(batch, gptr, N, B);
  k_deg<<<(E + 255) / 256, 256, 0, stream>>>(eidx, deg, E);
  k_lin0<<<(N * 64 + 255) / 256, 256, 0, stream>>>(x, lin0_w, lin0_b, outn, N);

  for (int it = 0; it < 3; ++it) {
    hipMemsetAsync(agg, 0, (size_t)N * 64 * 4, stream);
    k_msg<<<(E + TILE_E - 1) / TILE_E, 256, 0, stream>>>(
        eattr, eidx, nn1_w, nn1_b, nn2_w, nn2_b, outn, agg, E);
    k_conv_m<<<(N + 3) / 4, 256, 0, stream>>>(agg, deg, root_w, conv_b, outn,
                                              m_buf, N);
    k_gru<<<(N + 3) / 4, 256, 0, stream>>>(m_buf, gw_ih, gw_hh, gb_ih, gb_hh,
                                           outn, N);
  }

  for (int s = 0; s < 3; ++s) {
    k_lstm<<<B, 256, 0, stream>>>(lw_ih, lw_hh, lb_ih, lb_hh, qstar, hs, cs);
    k_attn<<<B, 64, 0, stream>>>(outn, gptr, hs, qstar);
  }
  k_read<<<B, 64, 0, stream>>>(qstar, lin1_w, lin1_b, lin2_w, lin2_b,
                               (float*)d_out);
}

// Round 2
// 3563.528 us; speedup vs baseline: 1.4520x; 1.4520x over previous
//
#include <hip/hip_runtime.h>
#include <math.h>

// ---------------------------------------------------------------------------
// MPNN (NNConv+GRU x3, Set2Set x3, readout) — factored formulation:
//   agg[n,o] = sum_m P[n,m] * Wbig[m,o],  m=(k,i), P = scatter outer(s, h1ext)
// N=20000, E=60000, DIM=64, B=512.  K-dim: 132*64 (edge part, cols 129..131
// zero) + 64 (root) + pad = 8704.
// ---------------------------------------------------------------------------

#define KTOT 8704
#define KQ   2176   // KTOT/4
#define KEDGE_Q 2112  // 132*64/4
#define KROOT_Q 2128  // (8448+64)/4

// graph segment pointers from sorted batch
__global__ void k_gptr(const int* __restrict__ batch, int* __restrict__ gptr,
                       int N, int B) {
  int n = blockIdx.x * 256 + threadIdx.x;
  if (n >= N) return;
  int b = batch[n];
  int bp = (n == 0) ? -1 : batch[n - 1];
  for (int g = bp + 1; g <= b; ++g) gptr[g] = n;
  if (n == N - 1) {
    for (int g = b + 1; g <= B; ++g) gptr[g] = N;
  }
}

__global__ void k_cnt(const int* __restrict__ eidx, int* __restrict__ cnt, int E) {
  int e = blockIdx.x * 256 + threadIdx.x;
  if (e < E) atomicAdd(&cnt[eidx[E + e]], 1);
}

// single-block inclusive scan -> dptr (exclusive CSR pointers)
__global__ __launch_bounds__(1024) void k_scan(const int* __restrict__ cnt,
                                               int* __restrict__ dptr, int N) {
  __shared__ int sm[1024];
  __shared__ int s_off;
  int t = threadIdx.x;
  if (t == 0) { s_off = 0; dptr[0] = 0; }
  __syncthreads();
  for (int base = 0; base < N; base += 1024) {
    int v = (base + t < N) ? cnt[base + t] : 0;
    sm[t] = v;
    __syncthreads();
    for (int d = 1; d < 1024; d <<= 1) {
      int add = (t >= d) ? sm[t - d] : 0;
      __syncthreads();
      sm[t] += add;
      __syncthreads();
    }
    int incl = sm[t];
    int tot = sm[1023];
    if (base + t < N) dptr[base + t + 1] = s_off + incl;
    __syncthreads();
    if (t == 0) s_off += tot;
    __syncthreads();
  }
}

__global__ void k_fill(const int* __restrict__ eidx, const int* __restrict__ dptr,
                       int* __restrict__ fill, int* __restrict__ srcs_s,
                       int* __restrict__ eord, int E) {
  int e = blockIdx.x * 256 + threadIdx.x;
  if (e >= E) return;
  int d = eidx[E + e];
  int pos = dptr[d] + atomicAdd(&fill[d], 1);
  srcs_s[pos] = eidx[e];
  eord[pos] = e;
}

// h1s[pos][0..131]: relu(edge MLP) for sorted edge order; col128=1, 129..131=0
__global__ __launch_bounds__(192) void k_h1(const float* __restrict__ eattr,
                                            const int* __restrict__ eord,
                                            const float* __restrict__ nn1_w,
                                            const float* __restrict__ nn1_b,
                                            float* __restrict__ h1s, int E) {
  int pos = blockIdx.x;
  int j = threadIdx.x;
  if (pos >= E || j >= 132) return;
  float v;
  if (j < 128) {
    int e = eord[pos];
    const float* a = eattr + (size_t)e * 5;
    const float* wr = nn1_w + j * 5;
    v = nn1_b[j] + a[0] * wr[0] + a[1] * wr[1] + a[2] * wr[2] + a[3] * wr[3] +
        a[4] * wr[4];
    v = fmaxf(v, 0.f);
  } else {
    v = (j == 128) ? 1.0f : 0.0f;
  }
  h1s[(size_t)pos * 132 + j] = v;
}

// Wbig[m][o], m = k*64+i (k<133), then root rows, then zero pad to 8704
__global__ void k_wbig(const float* __restrict__ nn2_w,
                       const float* __restrict__ nn2_b,
                       const float* __restrict__ root_w,
                       float* __restrict__ Wbig) {
  int gid = blockIdx.x * 256 + threadIdx.x;
  if (gid >= KTOT * 64) return;
  int m = gid >> 6, o = gid & 63;
  int k = m >> 6, i = m & 63;
  float v;
  if (k < 128) v = nn2_w[(size_t)(i * 64 + o) * 128 + k];
  else if (k == 128) v = nn2_b[i * 64 + o];
  else if (m >= 8448 && m < 8512) v = root_w[o * 64 + (m - 8448)];
  else v = 0.f;
  Wbig[(size_t)m * 64 + o] = v;
}

// out = relu(x @ lin0_w^T + lin0_b)
__global__ void k_lin0(const float* __restrict__ x, const float* __restrict__ w,
                       const float* __restrict__ b, float* __restrict__ outn, int N) {
  int gid = blockIdx.x * 256 + threadIdx.x;
  int n = gid >> 6, d = gid & 63;
  if (n >= N) return;
  const float* xr = x + (size_t)n * 11;
  const float* wr = w + d * 11;
  float acc = b[d];
#pragma unroll
  for (int f = 0; f < 11; ++f) acc += xr[f] * wr[f];
  outn[(size_t)n * 64 + d] = fmaxf(acc, 0.f);
}

// P-build: block per node; P[nl][m] = (1/deg) * sum_e s[e,i]*h1ext[e,k],
// then root cols = outn[n], then zero pad.
__global__ __launch_bounds__(256) void k_pbuild(
    const float* __restrict__ outn, const float* __restrict__ h1s,
    const int* __restrict__ dptr, const int* __restrict__ srcs_s,
    float4* __restrict__ P, int nbase, int Nn) {
  __shared__ __align__(16) float s_l[64];
  __shared__ float h1_l[132];
  int nl = blockIdx.x;
  if (nl >= Nn) return;
  int n = nbase + nl;
  int t = threadIdx.x;
  int p0 = dptr[n], p1 = dptr[n + 1];
  float inv = 1.f / (float)((p1 - p0) > 1 ? (p1 - p0) : 1);
  float4 acc[9];
#pragma unroll
  for (int j = 0; j < 9; ++j) acc[j] = make_float4(0.f, 0.f, 0.f, 0.f);

  const int kb = t >> 4;
  for (int pos = p0; pos < p1; ++pos) {
    __syncthreads();
    if (t < 64) {
      int src = srcs_s[pos];
      s_l[t] = outn[(size_t)src * 64 + t];
    } else if (t < 196) {
      h1_l[t - 64] = h1s[(size_t)pos * 132 + (t - 64)];
    }
    __syncthreads();
    float4 s4 = ((const float4*)s_l)[t & 15];
#pragma unroll
    for (int j = 0; j < 9; ++j) {
      int q = t + 256 * j;
      if (q < KEDGE_Q) {
        float h = h1_l[kb + 16 * j];
        acc[j].x += s4.x * h;
        acc[j].y += s4.y * h;
        acc[j].z += s4.z * h;
        acc[j].w += s4.w * h;
      }
    }
  }

  float4* row = P + (size_t)nl * KQ;
  const float4* on4 = (const float4*)(outn + (size_t)n * 64);
#pragma unroll
  for (int j = 0; j < 9; ++j) {
    int q = t + 256 * j;
    if (q < KEDGE_Q) {
      float4 v = acc[j];
      v.x *= inv; v.y *= inv; v.z *= inv; v.w *= inv;
      row[q] = v;
    } else if (q < KROOT_Q) {
      row[q] = on4[q - KEDGE_Q];
    } else if (q < KQ) {
      row[q] = make_float4(0.f, 0.f, 0.f, 0.f);
    }
  }
}

// GEMM: agg2[n,o] += sum_{k-chunk} P[nl][k]*Wbig[k][o]
// block: 256 thr = 4 waves; wave = 64 local nodes; thread 8n x 8o; split-K=8.
#define KT 32
#define KCHUNK 1088
__global__ __launch_bounds__(256, 3) void k_gemm(
    const float* __restrict__ P, const float* __restrict__ Wbig,
    float* __restrict__ agg2, int nbase, int Nn, int Ntot) {
  __shared__ __align__(16) float As[4][64 * 36];  // [wave][row][k], stride 36
  __shared__ __align__(16) float Bs[KT * 64];
  int t = threadIdx.x;
  int w = t >> 6, lane = t & 63;
  int ty = lane >> 3, tx = lane & 7;
  int n0 = blockIdx.x * 256 + w * 64;  // local node base for this wave
  int kbeg = blockIdx.y * KCHUNK;

  float acc[8][8];
#pragma unroll
  for (int r = 0; r < 8; ++r)
#pragma unroll
    for (int c = 0; c < 8; ++c) acc[r][c] = 0.f;

  for (int k0 = kbeg; k0 < kbeg + KCHUNK; k0 += KT) {
    __syncthreads();
    // stage A: this wave's 64 rows x KT
#pragma unroll
    for (int jj = 0; jj < 8; ++jj) {
      int idx = lane + 64 * jj;
      int row = idx >> 3, kq = idx & 7;
      float4 v = *(const float4*)(P + ((size_t)(n0 + row) * KTOT + k0 + kq * 4));
      *(float4*)&As[w][row * 36 + kq * 4] = v;
    }
    // stage B: all 256 threads
#pragma unroll
    for (int jj = 0; jj < 2; ++jj) {
      int idx = t + 256 * jj;
      int kk = idx >> 4, o4 = idx & 15;
      float4 v = *(const float4*)(Wbig + ((size_t)(k0 + kk) * 64 + o4 * 4));
      *(float4*)&Bs[kk * 64 + o4 * 4] = v;
    }
    __syncthreads();
#pragma unroll
    for (int kk = 0; kk < KT; ++kk) {
      float a[8];
#pragma unroll
      for (int r = 0; r < 8; ++r) a[r] = As[w][(ty * 8 + r) * 36 + kk];
      float4 b0 = *(const float4*)&Bs[kk * 64 + tx * 8];
      float4 b1 = *(const float4*)&Bs[kk * 64 + tx * 8 + 4];
      float bb[8] = {b0.x, b0.y, b0.z, b0.w, b1.x, b1.y, b1.z, b1.w};
#pragma unroll
      for (int r = 0; r < 8; ++r)
#pragma unroll
        for (int c = 0; c < 8; ++c) acc[r][c] += a[r] * bb[c];
    }
  }

#pragma unroll
  for (int r = 0; r < 8; ++r) {
    int nl = n0 + ty * 8 + r;
    int n = nbase + nl;
    if (nl < Nn && n < Ntot) {
      float* ap = agg2 + (size_t)n * 64 + tx * 8;
#pragma unroll
      for (int c = 0; c < 8; ++c) atomicAdd(ap + c, acc[r][c]);
    }
  }
}

// GRU step fused with conv epilogue: m = relu(agg2 + conv_b); out <- GRU(m, out)
__global__ __launch_bounds__(256) void k_gru(
    const float* __restrict__ agg2, const float* __restrict__ conv_b,
    const float* __restrict__ gw_ih, const float* __restrict__ gw_hh,
    const float* __restrict__ gb_ih, const float* __restrict__ gb_hh,
    float* __restrict__ outn, int N) {
  __shared__ float wT[32 * 385];
  const int t = threadIdx.x;
  const int wv = t >> 6, d = t & 63;
  const int n = blockIdx.x * 4 + wv;
  const bool act = (n < N);
  float m_d = act ? fmaxf(agg2[(size_t)n * 64 + d] + conv_b[d], 0.f) : 0.f;
  float h_d = act ? outn[(size_t)n * 64 + d] : 0.f;
  float ir = 0, iz = 0, in_ = 0, hr = 0, hz = 0, hn = 0;
  for (int half = 0; half < 2; ++half) {
    __syncthreads();
    for (int idx = t; idx < 192 * 32; idx += 256) {
      int g = idx >> 5, kl = idx & 31;
      wT[kl * 385 + g] = gw_ih[g * 64 + half * 32 + kl];
      wT[kl * 385 + 192 + g] = gw_hh[g * 64 + half * 32 + kl];
    }
    __syncthreads();
#pragma unroll
    for (int kl = 0; kl < 32; ++kl) {
      int k = half * 32 + kl;
      float mk = __shfl(m_d, k);
      float hk = __shfl(h_d, k);
      const float* row = &wT[kl * 385];
      ir += row[d] * mk;
      iz += row[64 + d] * mk;
      in_ += row[128 + d] * mk;
      hr += row[192 + d] * hk;
      hz += row[256 + d] * hk;
      hn += row[320 + d] * hk;
    }
  }
  if (act) {
    float r = 1.f / (1.f + expf(-(ir + gb_ih[d] + hr + gb_hh[d])));
    float z = 1.f / (1.f + expf(-(iz + gb_ih[64 + d] + hz + gb_hh[64 + d])));
    float nn = tanhf(in_ + gb_ih[128 + d] + r * (hn + gb_hh[128 + d]));
    outn[(size_t)n * 64 + d] = (1.f - z) * nn + z * h_d;
  }
}

// Set2Set LSTM step
__global__ __launch_bounds__(256) void k_lstm(
    const float* __restrict__ w_ih, const float* __restrict__ w_hh,
    const float* __restrict__ b_ih, const float* __restrict__ b_hh,
    const float* __restrict__ qstar, float* __restrict__ hs,
    float* __restrict__ cs) {
  __shared__ float gate[256];
  __shared__ float q[128];
  __shared__ float h[64];
  const int b = blockIdx.x, t = threadIdx.x;
  if (t < 128) q[t] = qstar[b * 128 + t];
  if (t < 64) h[t] = hs[b * 64 + t];
  __syncthreads();
  float acc = b_ih[t] + b_hh[t];
  const float* wi = w_ih + t * 128;
  const float* wh = w_hh + t * 64;
#pragma unroll 4
  for (int k = 0; k < 128; ++k) acc += wi[k] * q[k];
#pragma unroll 4
  for (int k = 0; k < 64; ++k) acc += wh[k] * h[k];
  gate[t] = acc;
  __syncthreads();
  if (t < 64) {
    float ig = gate[t], fg = gate[64 + t], gg = gate[128 + t], og = gate[192 + t];
    float c = cs[b * 64 + t];
    float si = 1.f / (1.f + expf(-ig));
    float sf = 1.f / (1.f + expf(-fg));
    float so = 1.f / (1.f + expf(-og));
    float cn = sf * c + si * tanhf(gg);
    cs[b * 64 + t] = cn;
    hs[b * 64 + t] = so * tanhf(cn);
  }
}

// Set2Set attention
__global__ __launch_bounds__(64) void k_attn(const float* __restrict__ outn,
                                             const int* __restrict__ gptr,
                                             const float* __restrict__ hs,
                                             float* __restrict__ qstar) {
  const int b = blockIdx.x, d = threadIdx.x;
  const int n0 = gptr[b], n1 = gptr[b + 1];
  float qd = hs[b * 64 + d];
  float mx = -3.4e38f;
  for (int n = n0; n < n1; ++n) {
    float v = outn[(size_t)n * 64 + d] * qd;
    for (int s = 32; s > 0; s >>= 1) v += __shfl_xor(v, s);
    mx = fmaxf(mx, v);
  }
  float denom = 0.f, racc = 0.f;
  for (int n = n0; n < n1; ++n) {
    float od = outn[(size_t)n * 64 + d];
    float v = od * qd;
    for (int s = 32; s > 0; s >>= 1) v += __shfl_xor(v, s);
    float a = expf(v - mx);
    denom += a;
    racc += a * od;
  }
  float r = (denom > 0.f) ? racc / denom : 0.f;
  qstar[b * 128 + d] = qd;
  qstar[b * 128 + 64 + d] = r;
}

// readout
__global__ __launch_bounds__(64) void k_read(const float* __restrict__ qstar,
                                             const float* __restrict__ w1,
                                             const float* __restrict__ b1,
                                             const float* __restrict__ w2,
                                             const float* __restrict__ b2,
                                             float* __restrict__ y) {
  const int b = blockIdx.x, d = threadIdx.x;
  const float* q = qstar + b * 128;
  const float* wr = w1 + d * 128;
  float acc = b1[d];
#pragma unroll 4
  for (int k = 0; k < 128; ++k) acc += wr[k] * q[k];
  acc = fmaxf(acc, 0.f) * w2[d];
  for (int s = 32; s > 0; s >>= 1) acc += __shfl_xor(acc, s);
  if (d == 0) y[b] = acc + b2[0];
}

extern "C" void kernel_launch(void* const* d_in, const int* in_sizes, int n_in,
                              void* d_out, int out_size, void* d_ws,
                              size_t ws_size, hipStream_t stream) {
  (void)n_in; (void)out_size;
  const float* x      = (const float*)d_in[0];
  const int*   eidx   = (const int*)d_in[1];
  const float* eattr  = (const float*)d_in[2];
  const int*   batch  = (const int*)d_in[3];
  const float* lin0_w = (const float*)d_in[4];
  const float* lin0_b = (const float*)d_in[5];
  const float* nn1_w  = (const float*)d_in[6];
  const float* nn1_b  = (const float*)d_in[7];
  const float* nn2_w  = (const float*)d_in[8];
  const float* nn2_b  = (const float*)d_in[9];
  const float* root_w = (const float*)d_in[10];
  const float* conv_b = (const float*)d_in[11];
  const float* gw_ih  = (const float*)d_in[12];
  const float* gw_hh  = (const float*)d_in[13];
  const float* gb_ih  = (const float*)d_in[14];
  const float* gb_hh  = (const float*)d_in[15];
  const float* lw_ih  = (const float*)d_in[16];
  const float* lw_hh  = (const float*)d_in[17];
  const float* lb_ih  = (const float*)d_in[18];
  const float* lb_hh  = (const float*)d_in[19];
  const float* lin1_w = (const float*)d_in[20];
  const float* lin1_b = (const float*)d_in[21];
  const float* lin2_w = (const float*)d_in[22];
  const float* lin2_b = (const float*)d_in[23];

  const int N = in_sizes[0] / 11;
  const int E = in_sizes[1] / 2;
  const int B = 512;

  size_t off = 0;
  auto bump = [&](size_t bytes) {
    size_t o = off;
    off += (bytes + 255) & ~(size_t)255;
    return o;
  };
  char* base = (char*)d_ws;
  float* outn   = (float*)(base + bump((size_t)N * 64 * 4));
  float* agg2   = (float*)(base + bump((size_t)N * 64 * 4));
  float* h1s    = (float*)(base + bump((size_t)E * 132 * 4));
  float* Wbig   = (float*)(base + bump((size_t)KTOT * 64 * 4));
  int*   cnt    = (int*)(base + bump((size_t)N * 4));
  int*   fill   = (int*)(base + bump((size_t)N * 4));
  int*   dptr   = (int*)(base + bump((size_t)(N + 1) * 4));
  int*   srcs_s = (int*)(base + bump((size_t)E * 4));
  int*   eord   = (int*)(base + bump((size_t)E * 4));
  float* qstar  = (float*)(base + bump((size_t)B * 128 * 4));
  float* hs     = (float*)(base + bump((size_t)B * 64 * 4));
  float* cs     = (float*)(base + bump((size_t)B * 64 * 4));
  int*   gptr   = (int*)(base + bump((size_t)(B + 1) * 4));
  size_t fixed = off;

  // P chunk: as many 256-node chunks as fit in remaining workspace
  size_t avail = (ws_size > fixed + 4096) ? (ws_size - fixed - 4096) : 0;
  long long rows = (long long)(avail / ((size_t)KTOT * 4));
  int NC = (int)((rows / 256) * 256);
  int NC_cap = ((N + 255) / 256) * 256;
  if (NC > NC_cap) NC = NC_cap;
  if (NC < 256) NC = 256;  // minimal fallback
  float* P = (float*)(base + bump((size_t)NC * KTOT * 4));

  hipMemsetAsync(cnt, 0, (size_t)N * 4, stream);
  hipMemsetAsync(fill, 0, (size_t)N * 4, stream);
  hipMemsetAsync(qstar, 0, (size_t)B * 128 * 4, stream);
  hipMemsetAsync(hs, 0, (size_t)B * 64 * 4, stream);
  hipMemsetAsync(cs, 0, (size_t)B * 64 * 4, stream);

  k_gptr<<<(N + 255) / 256, 256, 0, stream>>>(batch, gptr, N, B);
  k_cnt<<<(E + 255) / 256, 256, 0, stream>>>(eidx, cnt, E);
  k_scan<<<1, 1024, 0, stream>>>(cnt, dptr, N);
  k_fill<<<(E + 255) / 256, 256, 0, stream>>>(eidx, dptr, fill, srcs_s, eord, E);
  k_h1<<<E, 192, 0, stream>>>(eattr, eord, nn1_w, nn1_b, h1s, E);
  k_wbig<<<(KTOT * 64 + 255) / 256, 256, 0, stream>>>(nn2_w, nn2_b, root_w, Wbig);
  k_lin0<<<(N * 64 + 255) / 256, 256, 0, stream>>>(x, lin0_w, lin0_b, outn, N);

  for (int it = 0; it < 3; ++it) {
    hipMemsetAsync(agg2, 0, (size_t)N * 64 * 4, stream);
    for (int nb = 0; nb < N; nb += NC) {
      int cn = (N - nb < NC) ? (N - nb) : NC;
      int ntiles = (cn + 255) / 256;
      k_pbuild<<<cn, 256, 0, stream>>>(outn, h1s, dptr, srcs_s, (float4*)P, nb, cn);
      k_gemm<<<dim3(ntiles, KTOT / KCHUNK), 256, 0, stream>>>(P, Wbig, agg2, nb,
                                                              cn, N);
    }
    k_gru<<<(N + 3) / 4, 256, 0, stream>>>(agg2, conv_b, gw_ih, gw_hh, gb_ih,
                                           gb_hh, outn, N);
  }

  for (int s = 0; s < 3; ++s) {
    k_lstm<<<B, 256, 0, stream>>>(lw_ih, lw_hh, lb_ih, lb_hh, qstar, hs, cs);
    k_attn<<<B, 64, 0, stream>>>(outn, gptr, hs, qstar);
  }
  k_read<<<B, 64, 0, stream>>>(qstar, lin1_w, lin1_b, lin2_w, lin2_b,
                               (float*)d_out);
}

// Round 3
// 1813.682 us; speedup vs baseline: 2.8530x; 1.9648x over previous
//
#include <hip/hip_runtime.h>
#include <math.h>

// ---------------------------------------------------------------------------
// MPNN (NNConv+GRU x3, Set2Set x3, readout).
// Fused conv: per 64-node block, A[n,(k,i)] = sum_{e->n} h1[e,k]*s[e,i] built
// in registers, split fp16 hi/lo into LDS (MFMA A-frag order), contracted
// against pre-split Wbig frags with mfma_f32_16x16x32_f16 (3-pass split-fp16).
// K-chunks: 64 x (2 h1-cols) + bias chunk + root chunk = 66.
// ---------------------------------------------------------------------------

typedef _Float16 f16x8 __attribute__((ext_vector_type(8)));
typedef float f32x4 __attribute__((ext_vector_type(4)));

#define NCHUNK 66
#define BFRAG_TOTAL (66 * 4 * 4 * 64 * 8)  // 540672 halves per array

// graph segment pointers from sorted batch
__global__ void k_gptr(const int* __restrict__ batch, int* __restrict__ gptr,
                       int N, int B) {
  int n = blockIdx.x * 256 + threadIdx.x;
  if (n >= N) return;
  int b = batch[n];
  int bp = (n == 0) ? -1 : batch[n - 1];
  for (int g = bp + 1; g <= b; ++g) gptr[g] = n;
  if (n == N - 1) {
    for (int g = b + 1; g <= B; ++g) gptr[g] = N;
  }
}

__global__ void k_cnt(const int* __restrict__ eidx, int* __restrict__ cnt, int E) {
  int e = blockIdx.x * 256 + threadIdx.x;
  if (e < E) atomicAdd(&cnt[eidx[E + e]], 1);
}

// single-block inclusive scan -> dptr (exclusive CSR pointers)
__global__ __launch_bounds__(1024) void k_scan(const int* __restrict__ cnt,
                                               int* __restrict__ dptr, int N) {
  __shared__ int sm[1024];
  __shared__ int s_off;
  int t = threadIdx.x;
  if (t == 0) { s_off = 0; dptr[0] = 0; }
  __syncthreads();
  for (int base = 0; base < N; base += 1024) {
    int v = (base + t < N) ? cnt[base + t] : 0;
    sm[t] = v;
    __syncthreads();
    for (int d = 1; d < 1024; d <<= 1) {
      int add = (t >= d) ? sm[t - d] : 0;
      __syncthreads();
      sm[t] += add;
      __syncthreads();
    }
    int incl = sm[t];
    int tot = sm[1023];
    if (base + t < N) dptr[base + t + 1] = s_off + incl;
    __syncthreads();
    if (t == 0) s_off += tot;
    __syncthreads();
  }
}

__global__ void k_fill(const int* __restrict__ eidx, const int* __restrict__ dptr,
                       int* __restrict__ fill, int* __restrict__ srcs_s,
                       int* __restrict__ eord, int E) {
  int e = blockIdx.x * 256 + threadIdx.x;
  if (e >= E) return;
  int d = eidx[E + e];
  int pos = dptr[d] + atomicAdd(&fill[d], 1);
  srcs_s[pos] = eidx[e];
  eord[pos] = e;
}

// h1s[pos][0..127]: relu(edge MLP hidden) in dst-sorted edge order
__global__ __launch_bounds__(128) void k_h1(const float* __restrict__ eattr,
                                            const int* __restrict__ eord,
                                            const float* __restrict__ nn1_w,
                                            const float* __restrict__ nn1_b,
                                            float* __restrict__ h1s, int E) {
  int pos = blockIdx.x;
  int j = threadIdx.x;
  if (pos >= E) return;
  int e = eord[pos];
  const float* a = eattr + (size_t)e * 5;
  const float* wr = nn1_w + j * 5;
  float v = nn1_b[j] + a[0] * wr[0] + a[1] * wr[1] + a[2] * wr[2] +
            a[3] * wr[3] + a[4] * wr[4];
  h1s[(size_t)pos * 128 + j] = fmaxf(v, 0.f);
}

// Pre-split Wbig into fp16 hi/lo, stored in MFMA B-fragment order:
// flat idx = (((kc*4 + w)*4 + c)*64 + lane)*8 + j
// m = w*32 + (lane>>4)*8 + j ; o = c*16 + (lane&15) ; i=m&63 ; kl=m>>6
__global__ void k_bsplit(const float* __restrict__ nn2_w,
                         const float* __restrict__ nn2_b,
                         const float* __restrict__ root_w,
                         _Float16* __restrict__ Bh, _Float16* __restrict__ Bl) {
  int idx = blockIdx.x * 256 + threadIdx.x;
  if (idx >= BFRAG_TOTAL) return;
  int j = idx & 7;
  int lane = (idx >> 3) & 63;
  int c = (idx >> 9) & 3;
  int w = (idx >> 11) & 3;
  int kc = idx >> 13;
  int m = w * 32 + ((lane >> 4) << 3) + j;
  int o = c * 16 + (lane & 15);
  int i = m & 63, kl = m >> 6;
  float v;
  if (kc < 64)
    v = nn2_w[(size_t)(i * 64 + o) * 128 + (kc * 2 + kl)];
  else if (kc == 64)
    v = (kl == 0) ? nn2_b[i * 64 + o] : 0.f;
  else
    v = (kl == 0) ? root_w[o * 64 + i] : 0.f;
  _Float16 h = (_Float16)v;
  Bh[idx] = h;
  Bl[idx] = (_Float16)(v - (float)h);
}

// out = relu(x @ lin0_w^T + lin0_b)
__global__ void k_lin0(const float* __restrict__ x, const float* __restrict__ w,
                       const float* __restrict__ b, float* __restrict__ outn, int N) {
  int gid = blockIdx.x * 256 + threadIdx.x;
  int n = gid >> 6, d = gid & 63;
  if (n >= N) return;
  const float* xr = x + (size_t)n * 11;
  const float* wr = w + d * 11;
  float acc = b[d];
#pragma unroll
  for (int f = 0; f < 11; ++f) acc += xr[f] * wr[f];
  outn[(size_t)n * 64 + d] = fmaxf(acc, 0.f);
}

// ---------------- fused NNConv (build A + MFMA contract) -------------------
__global__ __launch_bounds__(256, 2) void k_fused(
    const float* __restrict__ outn, const float* __restrict__ h1s,
    const int* __restrict__ dptr, const int* __restrict__ srcs_s,
    const _Float16* __restrict__ Bh, const _Float16* __restrict__ Bl,
    float* __restrict__ agg2, int N) {
  __shared__ __align__(16) char smem[65536];
  _Float16* Ah = (_Float16*)smem;             // 64 nodes * 128 m = 16 KB
  _Float16* Al = (_Float16*)(smem + 16384);   // 16 KB
  float* Cred = (float*)smem;                 // epilogue overlay, 64 KB

  const int t = threadIdx.x;
  const int w = t >> 6, lane = t & 63;
  const int nl = t >> 2;   // builder node (0..63)
  const int iq = t & 3;    // i-quarter (16 cols)
  const int n0 = blockIdx.x * 64;
  const int n = n0 + nl;
  const bool nvalid = (n < N);
  int p0 = 0, p1 = 0;
  if (nvalid) { p0 = dptr[n]; p1 = dptr[n + 1]; }
  const float inv = 1.f / (float)((p1 - p0) > 1 ? (p1 - p0) : 1);
  const int rt_b = nl >> 4, nm = nl & 15;

  f32x4 acc[4][4];
#pragma unroll
  for (int a = 0; a < 4; ++a)
#pragma unroll
    for (int c = 0; c < 4; ++c) acc[a][c] = (f32x4)(0.f);

  for (int kc = 0; kc < NCHUNK; ++kc) {
    // ---- build this thread's 32 A-values (2 kl x 16 i) in registers ----
    float av[2][16];
#pragma unroll
    for (int kl = 0; kl < 2; ++kl)
#pragma unroll
      for (int j = 0; j < 16; ++j) av[kl][j] = 0.f;

    if (kc < 65) {
      for (int pos = p0; pos < p1; ++pos) {
        int src = srcs_s[pos];
        float h0, h1v;
        if (kc < 64) {
          const float* hp = h1s + (size_t)pos * 128 + kc * 2;
          h0 = hp[0];
          h1v = hp[1];
        } else {
          h0 = 1.f;  // bias chunk: h1ext = 1
          h1v = 0.f;
        }
        const float4* sp = (const float4*)(outn + (size_t)src * 64 + iq * 16);
        float4 s0 = sp[0], s1 = sp[1], s2 = sp[2], s3 = sp[3];
        float sv[16] = {s0.x, s0.y, s0.z, s0.w, s1.x, s1.y, s1.z, s1.w,
                        s2.x, s2.y, s2.z, s2.w, s3.x, s3.y, s3.z, s3.w};
#pragma unroll
        for (int j = 0; j < 16; ++j) {
          av[0][j] += h0 * sv[j];
          av[1][j] += h1v * sv[j];
        }
      }
#pragma unroll
      for (int kl = 0; kl < 2; ++kl)
#pragma unroll
        for (int j = 0; j < 16; ++j) av[kl][j] *= inv;  // /deg (edge part)
    } else {
      // root chunk: A[n][i] = outn[n][i], kl=1 half zero (no deg division)
      if (nvalid) {
        const float4* sp = (const float4*)(outn + (size_t)n * 64 + iq * 16);
        float4 s0 = sp[0], s1 = sp[1], s2 = sp[2], s3 = sp[3];
        float sv[16] = {s0.x, s0.y, s0.z, s0.w, s1.x, s1.y, s1.z, s1.w,
                        s2.x, s2.y, s2.z, s2.w, s3.x, s3.y, s3.z, s3.w};
#pragma unroll
        for (int j = 0; j < 16; ++j) av[0][j] = sv[j];
      }
    }

    // ---- split to fp16 hi/lo and write in A-frag order ----
#pragma unroll
    for (int kl = 0; kl < 2; ++kl) {
      int wb = kl * 2 + (iq >> 1);
#pragma unroll
      for (int g = 0; g < 2; ++g) {
        int q = (iq & 1) * 2 + g;
        int base = ((wb * 4 + rt_b) * 64 + (q << 4) + nm) * 8;
        f16x8 ph, pl;
#pragma unroll
        for (int jj = 0; jj < 8; ++jj) {
          float v = av[kl][g * 8 + jj];
          _Float16 h = (_Float16)v;
          ph[jj] = h;
          pl[jj] = (_Float16)(v - (float)h);
        }
        *(f16x8*)&Ah[base] = ph;
        *(f16x8*)&Al[base] = pl;
      }
    }
    __syncthreads();

    // ---- MFMA: wave w takes k-slice [w*32, w*32+32) of this chunk ----
    f16x8 ah[4], al[4];
#pragma unroll
    for (int rt = 0; rt < 4; ++rt) {
      ah[rt] = *(const f16x8*)&Ah[((w * 4 + rt) * 64 + lane) * 8];
      al[rt] = *(const f16x8*)&Al[((w * 4 + rt) * 64 + lane) * 8];
    }
    size_t bbase = ((size_t)(kc * 4 + w) * 4) * 512;  // + c*512 + lane*8
#pragma unroll
    for (int c = 0; c < 4; ++c) {
      f16x8 bh = *(const f16x8*)&Bh[bbase + c * 512 + lane * 8];
      f16x8 bl = *(const f16x8*)&Bl[bbase + c * 512 + lane * 8];
#pragma unroll
      for (int rt = 0; rt < 4; ++rt) {
        acc[rt][c] = __builtin_amdgcn_mfma_f32_16x16x32_f16(ah[rt], bh, acc[rt][c], 0, 0, 0);
        acc[rt][c] = __builtin_amdgcn_mfma_f32_16x16x32_f16(ah[rt], bl, acc[rt][c], 0, 0, 0);
        acc[rt][c] = __builtin_amdgcn_mfma_f32_16x16x32_f16(al[rt], bh, acc[rt][c], 0, 0, 0);
      }
    }
    __syncthreads();
  }

  // ---- epilogue: cross-wave K-reduction via LDS, then store ----
  const int qrow = (lane >> 4) * 4, col = lane & 15;
#pragma unroll
  for (int rt = 0; rt < 4; ++rt)
#pragma unroll
    for (int c = 0; c < 4; ++c)
#pragma unroll
      for (int r = 0; r < 4; ++r)
        Cred[w * 4096 + (rt * 16 + qrow + r) * 64 + c * 16 + col] = acc[rt][c][r];
  __syncthreads();
#pragma unroll
  for (int v4 = 0; v4 < 4; ++v4) {
    int idx = t * 16 + v4 * 4;
    int row = idx >> 6, cc = idx & 63;
    float4 s = *(float4*)&Cred[idx];
    float4 b = *(float4*)&Cred[4096 + idx];
    float4 c2 = *(float4*)&Cred[8192 + idx];
    float4 d = *(float4*)&Cred[12288 + idx];
    s.x += b.x + c2.x + d.x;
    s.y += b.y + c2.y + d.y;
    s.z += b.z + c2.z + d.z;
    s.w += b.w + c2.w + d.w;
    int nn = n0 + row;
    if (nn < N) *(float4*)&agg2[(size_t)nn * 64 + cc] = s;
  }
}

// GRU step fused with conv epilogue: m = relu(agg2 + conv_b); out <- GRU(m, out)
__global__ __launch_bounds__(256) void k_gru(
    const float* __restrict__ agg2, const float* __restrict__ conv_b,
    const float* __restrict__ gw_ih, const float* __restrict__ gw_hh,
    const float* __restrict__ gb_ih, const float* __restrict__ gb_hh,
    float* __restrict__ outn, int N) {
  __shared__ float wT[32 * 385];
  const int t = threadIdx.x;
  const int wv = t >> 6, d = t & 63;
  const int n = blockIdx.x * 4 + wv;
  const bool act = (n < N);
  float m_d = act ? fmaxf(agg2[(size_t)n * 64 + d] + conv_b[d], 0.f) : 0.f;
  float h_d = act ? outn[(size_t)n * 64 + d] : 0.f;
  float ir = 0, iz = 0, in_ = 0, hr = 0, hz = 0, hn = 0;
  for (int half = 0; half < 2; ++half) {
    __syncthreads();
    for (int idx = t; idx < 192 * 32; idx += 256) {
      int g = idx >> 5, kl = idx & 31;
      wT[kl * 385 + g] = gw_ih[g * 64 + half * 32 + kl];
      wT[kl * 385 + 192 + g] = gw_hh[g * 64 + half * 32 + kl];
    }
    __syncthreads();
#pragma unroll
    for (int kl = 0; kl < 32; ++kl) {
      int k = half * 32 + kl;
      float mk = __shfl(m_d, k);
      float hk = __shfl(h_d, k);
      const float* row = &wT[kl * 385];
      ir += row[d] * mk;
      iz += row[64 + d] * mk;
      in_ += row[128 + d] * mk;
      hr += row[192 + d] * hk;
      hz += row[256 + d] * hk;
      hn += row[320 + d] * hk;
    }
  }
  if (act) {
    float r = 1.f / (1.f + expf(-(ir + gb_ih[d] + hr + gb_hh[d])));
    float z = 1.f / (1.f + expf(-(iz + gb_ih[64 + d] + hz + gb_hh[64 + d])));
    float nn = tanhf(in_ + gb_ih[128 + d] + r * (hn + gb_hh[128 + d]));
    outn[(size_t)n * 64 + d] = (1.f - z) * nn + z * h_d;
  }
}

// Set2Set LSTM step
__global__ __launch_bounds__(256) void k_lstm(
    const float* __restrict__ w_ih, const float* __restrict__ w_hh,
    const float* __restrict__ b_ih, const float* __restrict__ b_hh,
    const float* __restrict__ qstar, float* __restrict__ hs,
    float* __restrict__ cs) {
  __shared__ float gate[256];
  __shared__ float q[128];
  __shared__ float h[64];
  const int b = blockIdx.x, t = threadIdx.x;
  if (t < 128) q[t] = qstar[b * 128 + t];
  if (t < 64) h[t] = hs[b * 64 + t];
  __syncthreads();
  float acc = b_ih[t] + b_hh[t];
  const float* wi = w_ih + t * 128;
  const float* wh = w_hh + t * 64;
#pragma unroll 4
  for (int k = 0; k < 128; ++k) acc += wi[k] * q[k];
#pragma unroll 4
  for (int k = 0; k < 64; ++k) acc += wh[k] * h[k];
  gate[t] = acc;
  __syncthreads();
  if (t < 64) {
    float ig = gate[t], fg = gate[64 + t], gg = gate[128 + t], og = gate[192 + t];
    float c = cs[b * 64 + t];
    float si = 1.f / (1.f + expf(-ig));
    float sf = 1.f / (1.f + expf(-fg));
    float so = 1.f / (1.f + expf(-og));
    float cn = sf * c + si * tanhf(gg);
    cs[b * 64 + t] = cn;
    hs[b * 64 + t] = so * tanhf(cn);
  }
}

// Set2Set attention
__global__ __launch_bounds__(64) void k_attn(const float* __restrict__ outn,
                                             const int* __restrict__ gptr,
                                             const float* __restrict__ hs,
                                             float* __restrict__ qstar) {
  const int b = blockIdx.x, d = threadIdx.x;
  const int n0 = gptr[b], n1 = gptr[b + 1];
  float qd = hs[b * 64 + d];
  float mx = -3.4e38f;
  for (int n = n0; n < n1; ++n) {
    float v = outn[(size_t)n * 64 + d] * qd;
    for (int s = 32; s > 0; s >>= 1) v += __shfl_xor(v, s);
    mx = fmaxf(mx, v);
  }
  float denom = 0.f, racc = 0.f;
  for (int n = n0; n < n1; ++n) {
    float od = outn[(size_t)n * 64 + d];
    float v = od * qd;
    for (int s = 32; s > 0; s >>= 1) v += __shfl_xor(v, s);
    float a = expf(v - mx);
    denom += a;
    racc += a * od;
  }
  float r = (denom > 0.f) ? racc / denom : 0.f;
  qstar[b * 128 + d] = qd;
  qstar[b * 128 + 64 + d] = r;
}

// readout
__global__ __launch_bounds__(64) void k_read(const float* __restrict__ qstar,
                                             const float* __restrict__ w1,
                                             const float* __restrict__ b1,
                                             const float* __restrict__ w2,
                                             const float* __restrict__ b2,
                                             float* __restrict__ y) {
  const int b = blockIdx.x, d = threadIdx.x;
  const float* q = qstar + b * 128;
  const float* wr = w1 + d * 128;
  float acc = b1[d];
#pragma unroll 4
  for (int k = 0; k < 128; ++k) acc += wr[k] * q[k];
  acc = fmaxf(acc, 0.f) * w2[d];
  for (int s = 32; s > 0; s >>= 1) acc += __shfl_xor(acc, s);
  if (d == 0) y[b] = acc + b2[0];
}

extern "C" void kernel_launch(void* const* d_in, const int* in_sizes, int n_in,
                              void* d_out, int out_size, void* d_ws,
                              size_t ws_size, hipStream_t stream) {
  (void)n_in; (void)out_size; (void)ws_size;
  const float* x      = (const float*)d_in[0];
  const int*   eidx   = (const int*)d_in[1];
  const float* eattr  = (const float*)d_in[2];
  const int*   batch  = (const int*)d_in[3];
  const float* lin0_w = (const float*)d_in[4];
  const float* lin0_b = (const float*)d_in[5];
  const float* nn1_w  = (const float*)d_in[6];
  const float* nn1_b  = (const float*)d_in[7];
  const float* nn2_w  = (const float*)d_in[8];
  const float* nn2_b  = (const float*)d_in[9];
  const float* root_w = (const float*)d_in[10];
  const float* conv_b = (const float*)d_in[11];
  const float* gw_ih  = (const float*)d_in[12];
  const float* gw_hh  = (const float*)d_in[13];
  const float* gb_ih  = (const float*)d_in[14];
  const float* gb_hh  = (const float*)d_in[15];
  const float* lw_ih  = (const float*)d_in[16];
  const float* lw_hh  = (const float*)d_in[17];
  const float* lb_ih  = (const float*)d_in[18];
  const float* lb_hh  = (const float*)d_in[19];
  const float* lin1_w = (const float*)d_in[20];
  const float* lin1_b = (const float*)d_in[21];
  const float* lin2_w = (const float*)d_in[22];
  const float* lin2_b = (const float*)d_in[23];

  const int N = in_sizes[0] / 11;
  const int E = in_sizes[1] / 2;
  const int B = 512;

  size_t off = 0;
  auto bump = [&](size_t bytes) {
    size_t o = off;
    off += (bytes + 255) & ~(size_t)255;
    return o;
  };
  char* base = (char*)d_ws;
  float*     outn   = (float*)(base + bump((size_t)N * 64 * 4));
  float*     agg2   = (float*)(base + bump((size_t)N * 64 * 4));
  float*     h1s    = (float*)(base + bump((size_t)E * 128 * 4));
  _Float16*  Bh     = (_Float16*)(base + bump((size_t)BFRAG_TOTAL * 2));
  _Float16*  Bl     = (_Float16*)(base + bump((size_t)BFRAG_TOTAL * 2));
  int*       cnt    = (int*)(base + bump((size_t)N * 4));
  int*       fill   = (int*)(base + bump((size_t)N * 4));
  int*       dptr   = (int*)(base + bump((size_t)(N + 1) * 4));
  int*       srcs_s = (int*)(base + bump((size_t)E * 4));
  int*       eord   = (int*)(base + bump((size_t)E * 4));
  float*     qstar  = (float*)(base + bump((size_t)B * 128 * 4));
  float*     hs     = (float*)(base + bump((size_t)B * 64 * 4));
  float*     cs     = (float*)(base + bump((size_t)B * 64 * 4));
  int*       gptr   = (int*)(base + bump((size_t)(B + 1) * 4));

  hipMemsetAsync(cnt, 0, (size_t)N * 4, stream);
  hipMemsetAsync(fill, 0, (size_t)N * 4, stream);
  hipMemsetAsync(qstar, 0, (size_t)B * 128 * 4, stream);
  hipMemsetAsync(hs, 0, (size_t)B * 64 * 4, stream);
  hipMemsetAsync(cs, 0, (size_t)B * 64 * 4, stream);

  k_gptr<<<(N + 255) / 256, 256, 0, stream>>>(batch, gptr, N, B);
  k_cnt<<<(E + 255) / 256, 256, 0, stream>>>(eidx, cnt, E);
  k_scan<<<1, 1024, 0, stream>>>(cnt, dptr, N);
  k_fill<<<(E + 255) / 256, 256, 0, stream>>>(eidx, dptr, fill, srcs_s, eord, E);
  k_h1<<<E, 128, 0, stream>>>(eattr, eord, nn1_w, nn1_b, h1s, E);
  k_bsplit<<<(BFRAG_TOTAL + 255) / 256, 256, 0, stream>>>(nn2_w, nn2_b, root_w,
                                                          Bh, Bl);
  k_lin0<<<(N * 64 + 255) / 256, 256, 0, stream>>>(x, lin0_w, lin0_b, outn, N);

  const int NBLK = (N + 63) / 64;
  for (int it = 0; it < 3; ++it) {
    k_fused<<<NBLK, 256, 0, stream>>>(outn, h1s, dptr, srcs_s, Bh, Bl, agg2, N);
    k_gru<<<(N + 3) / 4, 256, 0, stream>>>(agg2, conv_b, gw_ih, gw_hh, gb_ih,
                                           gb_hh, outn, N);
  }

  for (int s = 0; s < 3; ++s) {
    k_lstm<<<B, 256, 0, stream>>>(lw_ih, lw_hh, lb_ih, lb_hh, qstar, hs, cs);
    k_attn<<<B, 64, 0, stream>>>(outn, gptr, hs, qstar);
  }
  k_read<<<B, 64, 0, stream>>>(qstar, lin1_w, lin1_b, lin2_w, lin2_b,
                               (float*)d_out);
}

// Round 4
// 1181.506 us; speedup vs baseline: 4.3795x; 1.5351x over previous
//
#include <hip/hip_runtime.h>
#include <math.h>

// ---------------------------------------------------------------------------
// MPNN (NNConv+GRU x3, Set2Set x3, readout).
// Fused conv: per 64-node block, A[n,(k,i)] = sum_{e->n} h1[e,k]*s[e,i] built
// in registers, split fp16 hi/lo into LDS (MFMA A-frag order), contracted
// against pre-split Wbig frags with mfma_f32_16x16x32_f16 (3-pass split-fp16).
// R4: split-K x4 across blockIdx.y (atomicAdd epilogue), srcs + h staged in
// LDS (h double-buffered, k-major float2 layout), k_gru 16 nodes/block.
// ---------------------------------------------------------------------------

typedef _Float16 f16x8 __attribute__((ext_vector_type(8)));
typedef float f32x4 __attribute__((ext_vector_type(4)));

#define NCHUNK 66
#define BFRAG_TOTAL (66 * 4 * 4 * 64 * 8)  // 540672 halves per array
#define EMAXB 384                          // max edges per 64-node block (LDS path)

// graph segment pointers from sorted batch
__global__ void k_gptr(const int* __restrict__ batch, int* __restrict__ gptr,
                       int N, int B) {
  int n = blockIdx.x * 256 + threadIdx.x;
  if (n >= N) return;
  int b = batch[n];
  int bp = (n == 0) ? -1 : batch[n - 1];
  for (int g = bp + 1; g <= b; ++g) gptr[g] = n;
  if (n == N - 1) {
    for (int g = b + 1; g <= B; ++g) gptr[g] = N;
  }
}

__global__ void k_cnt(const int* __restrict__ eidx, int* __restrict__ cnt, int E) {
  int e = blockIdx.x * 256 + threadIdx.x;
  if (e < E) atomicAdd(&cnt[eidx[E + e]], 1);
}

// single-block inclusive scan -> dptr (exclusive CSR pointers)
__global__ __launch_bounds__(1024) void k_scan(const int* __restrict__ cnt,
                                               int* __restrict__ dptr, int N) {
  __shared__ int sm[1024];
  __shared__ int s_off;
  int t = threadIdx.x;
  if (t == 0) { s_off = 0; dptr[0] = 0; }
  __syncthreads();
  for (int base = 0; base < N; base += 1024) {
    int v = (base + t < N) ? cnt[base + t] : 0;
    sm[t] = v;
    __syncthreads();
    for (int d = 1; d < 1024; d <<= 1) {
      int add = (t >= d) ? sm[t - d] : 0;
      __syncthreads();
      sm[t] += add;
      __syncthreads();
    }
    int incl = sm[t];
    int tot = sm[1023];
    if (base + t < N) dptr[base + t + 1] = s_off + incl;
    __syncthreads();
    if (t == 0) s_off += tot;
    __syncthreads();
  }
}

__global__ void k_fill(const int* __restrict__ eidx, const int* __restrict__ dptr,
                       int* __restrict__ fill, int* __restrict__ srcs_s,
                       int* __restrict__ eord, int E) {
  int e = blockIdx.x * 256 + threadIdx.x;
  if (e >= E) return;
  int d = eidx[E + e];
  int pos = dptr[d] + atomicAdd(&fill[d], 1);
  srcs_s[pos] = eidx[e];
  eord[pos] = e;
}

// h1p[k>>1][pos] = float2(h1[pos][2k'], h1[pos][2k'+1]) : k-major pair layout
__global__ __launch_bounds__(256) void k_h1t(const float* __restrict__ eattr,
                                             const int* __restrict__ eord,
                                             const float* __restrict__ nn1_w,
                                             const float* __restrict__ nn1_b,
                                             float2* __restrict__ h1p, int E,
                                             int Epad) {
  __shared__ float a5[128 * 5];
  __shared__ float w5[128 * 5];
  __shared__ float bb[128];
  const int t = threadIdx.x;
  const int p0 = blockIdx.x * 128;
  for (int idx = t; idx < 640; idx += 256) w5[idx] = nn1_w[idx];
  if (t < 128) bb[t] = nn1_b[t];
  if (t < 128) {
    int pos = p0 + t;
    if (pos < E) {
      int e = eord[pos];
      const float* a = eattr + (size_t)e * 5;
#pragma unroll
      for (int q = 0; q < 5; ++q) a5[t * 5 + q] = a[q];
    } else {
#pragma unroll
      for (int q = 0; q < 5; ++q) a5[t * 5 + q] = 0.f;
    }
  }
  __syncthreads();
  const int pl = t & 127, jh = (t >> 7) * 64;
  const int pos = p0 + pl;
  if (pos >= E) return;
  float a0 = a5[pl * 5 + 0], a1 = a5[pl * 5 + 1], a2 = a5[pl * 5 + 2],
        a3 = a5[pl * 5 + 3], a4 = a5[pl * 5 + 4];
#pragma unroll 8
  for (int jj = 0; jj < 64; jj += 2) {
    int j = jh + jj;
    const float* w0 = &w5[j * 5];
    float v0 = fmaxf(bb[j] + a0 * w0[0] + a1 * w0[1] + a2 * w0[2] + a3 * w0[3] +
                         a4 * w0[4], 0.f);
    const float* w1 = &w5[(j + 1) * 5];
    float v1 = fmaxf(bb[j + 1] + a0 * w1[0] + a1 * w1[1] + a2 * w1[2] +
                         a3 * w1[3] + a4 * w1[4], 0.f);
    h1p[(size_t)(j >> 1) * Epad + pos] = make_float2(v0, v1);
  }
}

// Pre-split Wbig into fp16 hi/lo in MFMA B-fragment order:
// flat idx = (((kc*4 + w)*4 + c)*64 + lane)*8 + j
__global__ void k_bsplit(const float* __restrict__ nn2_w,
                         const float* __restrict__ nn2_b,
                         const float* __restrict__ root_w,
                         _Float16* __restrict__ Bh, _Float16* __restrict__ Bl) {
  int idx = blockIdx.x * 256 + threadIdx.x;
  if (idx >= BFRAG_TOTAL) return;
  int j = idx & 7;
  int lane = (idx >> 3) & 63;
  int c = (idx >> 9) & 3;
  int w = (idx >> 11) & 3;
  int kc = idx >> 13;
  int m = w * 32 + ((lane >> 4) << 3) + j;
  int o = c * 16 + (lane & 15);
  int i = m & 63, kl = m >> 6;
  float v;
  if (kc < 64)
    v = nn2_w[(size_t)(i * 64 + o) * 128 + (kc * 2 + kl)];
  else if (kc == 64)
    v = (kl == 0) ? nn2_b[i * 64 + o] : 0.f;
  else
    v = (kl == 0) ? root_w[o * 64 + i] : 0.f;
  _Float16 h = (_Float16)v;
  Bh[idx] = h;
  Bl[idx] = (_Float16)(v - (float)h);
}

// out = relu(x @ lin0_w^T + lin0_b)
__global__ void k_lin0(const float* __restrict__ x, const float* __restrict__ w,
                       const float* __restrict__ b, float* __restrict__ outn, int N) {
  int gid = blockIdx.x * 256 + threadIdx.x;
  int n = gid >> 6, d = gid & 63;
  if (n >= N) return;
  const float* xr = x + (size_t)n * 11;
  const float* wr = w + d * 11;
  float acc = b[d];
#pragma unroll
  for (int f = 0; f < 11; ++f) acc += xr[f] * wr[f];
  outn[(size_t)n * 64 + d] = fmaxf(acc, 0.f);
}

// ---------------- fused NNConv (build A + MFMA contract), split-K x4 -------
__global__ __launch_bounds__(256, 3) void k_fused(
    const float* __restrict__ outn, const float2* __restrict__ h1p,
    const int* __restrict__ dptr, const int* __restrict__ srcs_s,
    const _Float16* __restrict__ Bh, const _Float16* __restrict__ Bl,
    float* __restrict__ agg2, int N, int Epad) {
  __shared__ __align__(16) _Float16 Ah[16 * 64 * 8];  // 16 KB
  __shared__ __align__(16) _Float16 Al[16 * 64 * 8];  // 16 KB
  __shared__ __align__(16) float2 hbuf[2][EMAXB];     // 6 KB
  __shared__ int sSrc[EMAXB];                         // 1.5 KB

  const int t = threadIdx.x;
  const int w = t >> 6, lane = t & 63;
  const int nl = t >> 2;   // builder node (0..63)
  const int iq = t & 3;    // i-quarter (16 cols)
  const int split = blockIdx.y;
  const int n0 = blockIdx.x * 64;
  const int n = n0 + nl;
  const bool nvalid = (n < N);
  const int hi_n = (n0 + 64 > N) ? N : (n0 + 64);
  const int p0b = dptr[n0];
  const int p1b = dptr[hi_n];
  const int EB = p1b - p0b;
  const bool useLds = (EB <= EMAXB);
  int p0 = 0, p1 = 0;
  if (nvalid) { p0 = dptr[n]; p1 = dptr[n + 1]; }
  const float inv = 1.f / (float)((p1 - p0) > 1 ? (p1 - p0) : 1);
  const int rt_b = nl >> 4, nm = nl & 15;
  const int EBs = useLds ? EB : 0;

  // ---- stage src list + first h chunk ----
  for (int idx = t; idx < EBs; idx += 256) sSrc[idx] = srcs_s[p0b + idx];
  {
    const float2* hc = h1p + (size_t)(split * 16) * Epad;
    for (int idx = t; idx < EBs; idx += 256) hbuf[0][idx] = hc[p0b + idx];
  }
  __syncthreads();

  f32x4 acc[4][4];
#pragma unroll
  for (int a = 0; a < 4; ++a)
#pragma unroll
    for (int c = 0; c < 4; ++c) acc[a][c] = (f32x4)(0.f);

  const int niter = (split < 2) ? 17 : 16;
  int cur = 0;
  for (int cc = 0; cc < niter; ++cc) {
    const int mode = (cc < 16) ? 0 : ((split == 0) ? 1 : 2);
    const int kc = (cc < 16) ? (split * 16 + cc) : ((split == 0) ? 64 : 65);

    // ---- build this thread's 32 A-values (2 kl x 16 i) ----
    float av0[16], av1[16];
#pragma unroll
    for (int j = 0; j < 16; ++j) { av0[j] = 0.f; av1[j] = 0.f; }

    if (mode != 2) {
      const float2* hc = h1p + (size_t)kc * Epad;
      for (int pos = p0; pos < p1; ++pos) {
        float2 h;
        if (mode == 1) h = make_float2(1.f, 0.f);
        else h = useLds ? hbuf[cur][pos - p0b] : hc[pos];
        int src = useLds ? sSrc[pos - p0b] : srcs_s[pos];
        const float4* sp = (const float4*)(outn + (size_t)src * 64 + iq * 16);
        float4 s0 = sp[0], s1 = sp[1], s2 = sp[2], s3 = sp[3];
        float sv[16] = {s0.x, s0.y, s0.z, s0.w, s1.x, s1.y, s1.z, s1.w,
                        s2.x, s2.y, s2.z, s2.w, s3.x, s3.y, s3.z, s3.w};
#pragma unroll
        for (int j = 0; j < 16; ++j) {
          av0[j] += h.x * sv[j];
          av1[j] += h.y * sv[j];
        }
      }
#pragma unroll
      for (int j = 0; j < 16; ++j) { av0[j] *= inv; av1[j] *= inv; }
    } else {
      if (nvalid) {
        const float4* sp = (const float4*)(outn + (size_t)n * 64 + iq * 16);
        float4 s0 = sp[0], s1 = sp[1], s2 = sp[2], s3 = sp[3];
        float sv[16] = {s0.x, s0.y, s0.z, s0.w, s1.x, s1.y, s1.z, s1.w,
                        s2.x, s2.y, s2.z, s2.w, s3.x, s3.y, s3.z, s3.w};
#pragma unroll
        for (int j = 0; j < 16; ++j) av0[j] = sv[j];
      }
    }

    // ---- split fp16 hi/lo, write A-frag order ----
#pragma unroll
    for (int kl = 0; kl < 2; ++kl) {
      const float* av = kl ? av1 : av0;
      int wb = kl * 2 + (iq >> 1);
#pragma unroll
      for (int g = 0; g < 2; ++g) {
        int q = (iq & 1) * 2 + g;
        int base = ((wb * 4 + rt_b) * 64 + (q << 4) + nm) * 8;
        f16x8 ph, pl;
#pragma unroll
        for (int jj = 0; jj < 8; ++jj) {
          float v = av[g * 8 + jj];
          _Float16 h = (_Float16)v;
          ph[jj] = h;
          pl[jj] = (_Float16)(v - (float)h);
        }
        *(f16x8*)&Ah[base] = ph;
        *(f16x8*)&Al[base] = pl;
      }
    }
    __syncthreads();

    // ---- MFMA (wave w = k-slice) + prefetch next h chunk ----
    f16x8 ah[4], al[4];
#pragma unroll
    for (int rt = 0; rt < 4; ++rt) {
      ah[rt] = *(const f16x8*)&Ah[((w * 4 + rt) * 64 + lane) * 8];
      al[rt] = *(const f16x8*)&Al[((w * 4 + rt) * 64 + lane) * 8];
    }
    if (cc + 1 < 16) {
      const float2* hc = h1p + (size_t)(split * 16 + cc + 1) * Epad;
      for (int idx = t; idx < EBs; idx += 256) hbuf[cur ^ 1][idx] = hc[p0b + idx];
    }
    size_t bbase = ((size_t)(kc * 4 + w) * 4) * 512;
#pragma unroll
    for (int c = 0; c < 4; ++c) {
      f16x8 bh = *(const f16x8*)&Bh[bbase + c * 512 + lane * 8];
      f16x8 bl = *(const f16x8*)&Bl[bbase + c * 512 + lane * 8];
#pragma unroll
      for (int rt = 0; rt < 4; ++rt) {
        acc[rt][c] = __builtin_amdgcn_mfma_f32_16x16x32_f16(ah[rt], bh, acc[rt][c], 0, 0, 0);
        acc[rt][c] = __builtin_amdgcn_mfma_f32_16x16x32_f16(ah[rt], bl, acc[rt][c], 0, 0, 0);
        acc[rt][c] = __builtin_amdgcn_mfma_f32_16x16x32_f16(al[rt], bh, acc[rt][c], 0, 0, 0);
      }
    }
    __syncthreads();
    if (cc + 1 < 16) cur ^= 1;
  }

  // ---- epilogue: direct atomic accumulate ----
  const int qrow = (lane >> 4) * 4, col = lane & 15;
#pragma unroll
  for (int rt = 0; rt < 4; ++rt) {
#pragma unroll
    for (int r = 0; r < 4; ++r) {
      int nn = n0 + rt * 16 + qrow + r;
      if (nn < N) {
        float* ap = agg2 + (size_t)nn * 64 + col;
#pragma unroll
        for (int c = 0; c < 4; ++c) atomicAdd(ap + c * 16, acc[rt][c][r]);
      }
    }
  }
}

// GRU step (16 nodes/block, 4 per wave): m = relu(agg2+conv_b); out <- GRU
__global__ __launch_bounds__(256) void k_gru(
    const float* __restrict__ agg2, const float* __restrict__ conv_b,
    const float* __restrict__ gw_ih, const float* __restrict__ gw_hh,
    const float* __restrict__ gb_ih, const float* __restrict__ gb_hh,
    float* __restrict__ outn, int N) {
  __shared__ float wT[32 * 385];
  const int t = threadIdx.x;
  const int wv = t >> 6, d = t & 63;
  const int nbase = blockIdx.x * 16 + wv * 4;
  float m_d[4], h_d[4];
  bool act[4];
#pragma unroll
  for (int j = 0; j < 4; ++j) {
    int n = nbase + j;
    act[j] = (n < N);
    m_d[j] = act[j] ? fmaxf(agg2[(size_t)n * 64 + d] + conv_b[d], 0.f) : 0.f;
    h_d[j] = act[j] ? outn[(size_t)n * 64 + d] : 0.f;
  }
  float ir[4] = {0, 0, 0, 0}, iz[4] = {0, 0, 0, 0}, in_[4] = {0, 0, 0, 0};
  float hr[4] = {0, 0, 0, 0}, hz[4] = {0, 0, 0, 0}, hn[4] = {0, 0, 0, 0};
  for (int half = 0; half < 2; ++half) {
    __syncthreads();
    for (int idx = t; idx < 192 * 32; idx += 256) {
      int g = idx >> 5, kl = idx & 31;
      wT[kl * 385 + g] = gw_ih[g * 64 + half * 32 + kl];
      wT[kl * 385 + 192 + g] = gw_hh[g * 64 + half * 32 + kl];
    }
    __syncthreads();
#pragma unroll
    for (int kl = 0; kl < 32; ++kl) {
      int k = half * 32 + kl;
      const float* row = &wT[kl * 385];
      float r0 = row[d], r1 = row[64 + d], r2 = row[128 + d];
      float r3 = row[192 + d], r4 = row[256 + d], r5 = row[320 + d];
#pragma unroll
      for (int j = 0; j < 4; ++j) {
        float mk = __shfl(m_d[j], k);
        float hk = __shfl(h_d[j], k);
        ir[j] += r0 * mk;
        iz[j] += r1 * mk;
        in_[j] += r2 * mk;
        hr[j] += r3 * hk;
        hz[j] += r4 * hk;
        hn[j] += r5 * hk;
      }
    }
  }
#pragma unroll
  for (int j = 0; j < 4; ++j) {
    if (act[j]) {
      int n = nbase + j;
      float r = 1.f / (1.f + expf(-(ir[j] + gb_ih[d] + hr[j] + gb_hh[d])));
      float z = 1.f / (1.f + expf(-(iz[j] + gb_ih[64 + d] + hz[j] + gb_hh[64 + d])));
      float nn = tanhf(in_[j] + gb_ih[128 + d] + r * (hn[j] + gb_hh[128 + d]));
      outn[(size_t)n * 64 + d] = (1.f - z) * nn + z * h_d[j];
    }
  }
}

// Set2Set LSTM step
__global__ __launch_bounds__(256) void k_lstm(
    const float* __restrict__ w_ih, const float* __restrict__ w_hh,
    const float* __restrict__ b_ih, const float* __restrict__ b_hh,
    const float* __restrict__ qstar, float* __restrict__ hs,
    float* __restrict__ cs) {
  __shared__ float gate[256];
  __shared__ float q[128];
  __shared__ float h[64];
  const int b = blockIdx.x, t = threadIdx.x;
  if (t < 128) q[t] = qstar[b * 128 + t];
  if (t < 64) h[t] = hs[b * 64 + t];
  __syncthreads();
  float acc = b_ih[t] + b_hh[t];
  const float* wi = w_ih + t * 128;
  const float* wh = w_hh + t * 64;
#pragma unroll 4
  for (int k = 0; k < 128; ++k) acc += wi[k] * q[k];
#pragma unroll 4
  for (int k = 0; k < 64; ++k) acc += wh[k] * h[k];
  gate[t] = acc;
  __syncthreads();
  if (t < 64) {
    float ig = gate[t], fg = gate[64 + t], gg = gate[128 + t], og = gate[192 + t];
    float c = cs[b * 64 + t];
    float si = 1.f / (1.f + expf(-ig));
    float sf = 1.f / (1.f + expf(-fg));
    float so = 1.f / (1.f + expf(-og));
    float cn = sf * c + si * tanhf(gg);
    cs[b * 64 + t] = cn;
    hs[b * 64 + t] = so * tanhf(cn);
  }
}

// Set2Set attention
__global__ __launch_bounds__(64) void k_attn(const float* __restrict__ outn,
                                             const int* __restrict__ gptr,
                                             const float* __restrict__ hs,
                                             float* __restrict__ qstar) {
  const int b = blockIdx.x, d = threadIdx.x;
  const int n0 = gptr[b], n1 = gptr[b + 1];
  float qd = hs[b * 64 + d];
  float mx = -3.4e38f;
  for (int n = n0; n < n1; ++n) {
    float v = outn[(size_t)n * 64 + d] * qd;
    for (int s = 32; s > 0; s >>= 1) v += __shfl_xor(v, s);
    mx = fmaxf(mx, v);
  }
  float denom = 0.f, racc = 0.f;
  for (int n = n0; n < n1; ++n) {
    float od = outn[(size_t)n * 64 + d];
    float v = od * qd;
    for (int s = 32; s > 0; s >>= 1) v += __shfl_xor(v, s);
    float a = expf(v - mx);
    denom += a;
    racc += a * od;
  }
  float r = (denom > 0.f) ? racc / denom : 0.f;
  qstar[b * 128 + d] = qd;
  qstar[b * 128 + 64 + d] = r;
}

// readout
__global__ __launch_bounds__(64) void k_read(const float* __restrict__ qstar,
                                             const float* __restrict__ w1,
                                             const float* __restrict__ b1,
                                             const float* __restrict__ w2,
                                             const float* __restrict__ b2,
                                             float* __restrict__ y) {
  const int b = blockIdx.x, d = threadIdx.x;
  const float* q = qstar + b * 128;
  const float* wr = w1 + d * 128;
  float acc = b1[d];
#pragma unroll 4
  for (int k = 0; k < 128; ++k) acc += wr[k] * q[k];
  acc = fmaxf(acc, 0.f) * w2[d];
  for (int s = 32; s > 0; s >>= 1) acc += __shfl_xor(acc, s);
  if (d == 0) y[b] = acc + b2[0];
}

extern "C" void kernel_launch(void* const* d_in, const int* in_sizes, int n_in,
                              void* d_out, int out_size, void* d_ws,
                              size_t ws_size, hipStream_t stream) {
  (void)n_in; (void)out_size; (void)ws_size;
  const float* x      = (const float*)d_in[0];
  const int*   eidx   = (const int*)d_in[1];
  const float* eattr  = (const float*)d_in[2];
  const int*   batch  = (const int*)d_in[3];
  const float* lin0_w = (const float*)d_in[4];
  const float* lin0_b = (const float*)d_in[5];
  const float* nn1_w  = (const float*)d_in[6];
  const float* nn1_b  = (const float*)d_in[7];
  const float* nn2_w  = (const float*)d_in[8];
  const float* nn2_b  = (const float*)d_in[9];
  const float* root_w = (const float*)d_in[10];
  const float* conv_b = (const float*)d_in[11];
  const float* gw_ih  = (const float*)d_in[12];
  const float* gw_hh  = (const float*)d_in[13];
  const float* gb_ih  = (const float*)d_in[14];
  const float* gb_hh  = (const float*)d_in[15];
  const float* lw_ih  = (const float*)d_in[16];
  const float* lw_hh  = (const float*)d_in[17];
  const float* lb_ih  = (const float*)d_in[18];
  const float* lb_hh  = (const float*)d_in[19];
  const float* lin1_w = (const float*)d_in[20];
  const float* lin1_b = (const float*)d_in[21];
  const float* lin2_w = (const float*)d_in[22];
  const float* lin2_b = (const float*)d_in[23];

  const int N = in_sizes[0] / 11;
  const int E = in_sizes[1] / 2;
  const int B = 512;
  const int Epad = (E + 127) & ~127;

  size_t off = 0;
  auto bump = [&](size_t bytes) {
    size_t o = off;
    off += (bytes + 255) & ~(size_t)255;
    return o;
  };
  char* base = (char*)d_ws;
  float*     outn   = (float*)(base + bump((size_t)N * 64 * 4));
  float*     agg2   = (float*)(base + bump((size_t)N * 64 * 4));
  float2*    h1p    = (float2*)(base + bump((size_t)64 * Epad * 8));
  _Float16*  Bh     = (_Float16*)(base + bump((size_t)BFRAG_TOTAL * 2));
  _Float16*  Bl     = (_Float16*)(base + bump((size_t)BFRAG_TOTAL * 2));
  int*       cnt    = (int*)(base + bump((size_t)N * 4));
  int*       fill   = (int*)(base + bump((size_t)N * 4));
  int*       dptr   = (int*)(base + bump((size_t)(N + 1) * 4));
  int*       srcs_s = (int*)(base + bump((size_t)E * 4));
  int*       eord   = (int*)(base + bump((size_t)E * 4));
  float*     qstar  = (float*)(base + bump((size_t)B * 128 * 4));
  float*     hs     = (float*)(base + bump((size_t)B * 64 * 4));
  float*     cs     = (float*)(base + bump((size_t)B * 64 * 4));
  int*       gptr   = (int*)(base + bump((size_t)(B + 1) * 4));

  hipMemsetAsync(cnt, 0, (size_t)N * 4, stream);
  hipMemsetAsync(fill, 0, (size_t)N * 4, stream);
  hipMemsetAsync(qstar, 0, (size_t)B * 128 * 4, stream);
  hipMemsetAsync(hs, 0, (size_t)B * 64 * 4, stream);
  hipMemsetAsync(cs, 0, (size_t)B * 64 * 4, stream);

  k_gptr<<<(N + 255) / 256, 256, 0, stream>>>(batch, gptr, N, B);
  k_cnt<<<(E + 255) / 256, 256, 0, stream>>>(eidx, cnt, E);
  k_scan<<<1, 1024, 0, stream>>>(cnt, dptr, N);
  k_fill<<<(E + 255) / 256, 256, 0, stream>>>(eidx, dptr, fill, srcs_s, eord, E);
  k_h1t<<<(E + 127) / 128, 256, 0, stream>>>(eattr, eord, nn1_w, nn1_b, h1p, E,
                                             Epad);
  k_bsplit<<<(BFRAG_TOTAL + 255) / 256, 256, 0, stream>>>(nn2_w, nn2_b, root_w,
                                                          Bh, Bl);
  k_lin0<<<(N * 64 + 255) / 256, 256, 0, stream>>>(x, lin0_w, lin0_b, outn, N);

  const int NBLK = (N + 63) / 64;
  for (int it = 0; it < 3; ++it) {
    hipMemsetAsync(agg2, 0, (size_t)N * 64 * 4, stream);
    k_fused<<<dim3(NBLK, 4), 256, 0, stream>>>(outn, h1p, dptr, srcs_s, Bh, Bl,
                                               agg2, N, Epad);
    k_gru<<<(N + 15) / 16, 256, 0, stream>>>(agg2, conv_b, gw_ih, gw_hh, gb_ih,
                                             gb_hh, outn, N);
  }

  for (int s = 0; s < 3; ++s) {
    k_lstm<<<B, 256, 0, stream>>>(lw_ih, lw_hh, lb_ih, lb_hh, qstar, hs, cs);
    k_attn<<<B, 64, 0, stream>>>(outn, gptr, hs, qstar);
  }
  k_read<<<B, 64, 0, stream>>>(qstar, lin1_w, lin1_b, lin2_w, lin2_b,
                               (float*)d_out);
}